// Round 5
// baseline (246.920 us; speedup 1.0000x reference)
//
#include <hip/hip_runtime.h>
#include <hip/hip_cooperative_groups.h>

namespace cg = cooperative_groups;

#define NB 32
#define NC 256
#define NL 128   // NH+NW
#define NCM 128
#define NCO 256
#define NPLANES (NB * NC)   // 8192

typedef float v4f __attribute__((ext_vector_type(4)));

// ================= Fused cooperative kernel (grid-size-agnostic) =============
__global__ __launch_bounds__(256, 4) void k_fused(
    const float* __restrict__ x,
    const float* __restrict__ w1, const float* __restrict__ b1,
    const float* __restrict__ gam, const float* __restrict__ bet,
    const float* __restrict__ mu, const float* __restrict__ var,
    const float* __restrict__ w2, const float* __restrict__ b2,
    const float* __restrict__ w3, const float* __restrict__ b3,
    float* __restrict__ pool, float* __restrict__ a,
    float* __restrict__ gh, float* __restrict__ gw,
    float* __restrict__ out)
{
    cg::grid_group grid = cg::this_grid();
    __shared__ float smem[4608];          // 18.4 KB: max over phases
    const int G = gridDim.x;
    const int blk = blockIdx.x;
    const int t = threadIdx.x;

    // ---------------- Phase 1: pooling ----------------
    for (int plane = blk; plane < NPLANES; plane += G) {
        const float4* px = (const float4*)(x + (size_t)plane * 4096);
        float4 csum = make_float4(0.f, 0.f, 0.f, 0.f);
        #pragma unroll
        for (int i = 0; i < 4; ++i) {
            int f = t + i * 256;
            float4 v = px[f];
            csum.x += v.x; csum.y += v.y; csum.z += v.z; csum.w += v.w;
            float s = v.x + v.y + v.z + v.w;
            s += __shfl_xor(s, 1);
            s += __shfl_xor(s, 2);
            s += __shfl_xor(s, 4);
            s += __shfl_xor(s, 8);
            if ((t & 15) == 0)
                pool[(size_t)plane * NL + (t >> 4) + 16 * i] = s * 0.015625f; // xh
        }
        ((float4*)smem)[t] = csum;
        __syncthreads();
        if (t < 64) {
            float acc = 0.f;
            #pragma unroll
            for (int g = 0; g < 16; ++g)
                acc += smem[((t >> 2) + 16 * g) * 4 + (t & 3)];
            pool[(size_t)plane * NL + 64 + t] = acc * 0.015625f;  // xw
        }
        __syncthreads();
    }
    grid.sync();

    // ---------------- Phase 2: mlp1 (256 units: b x 8 m-tiles) ----------------
    for (int u = blk; u < 256; u += G) {
        int b = u >> 3, m0 = (u & 7) * 16;
        float* w1t = smem;            // [32][16]  c-major
        float* pt  = smem + 512;      // [32][128] c-major
        const float* poolb = pool + (size_t)b * NC * NL;
        int tm = t & 7;               // 8 m-groups of 2
        int tl = t >> 3;              // 32 l-groups of 4
        float acc[2][4] = {};
        for (int cc = 0; cc < NC; cc += 32) {
            {
                int mi = t & 15, c0 = (t >> 4) * 2;
                float2 wv = *(const float2*)(w1 + (size_t)(m0 + mi) * NC + cc + c0);
                w1t[(c0 + 0) * 16 + mi] = wv.x;
                w1t[(c0 + 1) * 16 + mi] = wv.y;
            }
            #pragma unroll
            for (int i = 0; i < 4; ++i) {
                int f = t + i * 256;
                int ci = f >> 5, l4 = f & 31;
                *(float4*)&pt[ci * 128 + l4 * 4] =
                    *(const float4*)(poolb + (size_t)(cc + ci) * NL + l4 * 4);
            }
            __syncthreads();
            #pragma unroll
            for (int cj = 0; cj < 32; ++cj) {
                float2 wv = *(const float2*)&w1t[cj * 16 + tm * 2];
                float4 pv = *(const float4*)&pt[cj * 128 + tl * 4];
                float pa[4] = {pv.x, pv.y, pv.z, pv.w};
                #pragma unroll
                for (int j = 0; j < 4; ++j) {
                    acc[0][j] += wv.x * pa[j];
                    acc[1][j] += wv.y * pa[j];
                }
            }
            __syncthreads();
        }
        #pragma unroll
        for (int i = 0; i < 2; ++i) {
            int m = m0 + tm * 2 + i;
            float scale = gam[m] * rsqrtf(var[m] + 1e-5f);
            float base = b1[m] - mu[m];
            float bb = bet[m];
            #pragma unroll
            for (int j = 0; j < 4; ++j) {
                float y = (acc[i][j] + base) * scale + bb;
                float hs = y * fminf(fmaxf(y + 3.f, 0.f), 6.f) * (1.f / 6.f);
                a[(size_t)b * NCM * NL + (size_t)m * NL + tl * 4 + j] = hs;
            }
        }
    }
    grid.sync();

    // ---------------- Phase 3: gates (512 units: b x side x 8 o-tiles) --------
    for (int u = blk; u < 512; u += G) {
        int b = u >> 4, side = (u >> 3) & 1, ot = u & 7;
        const float* wsel = side ? w3 : w2;
        const float* bsel = side ? b3 : b2;
        float* gsel = side ? gw : gh;
        float* wt = smem;             // [32][32] k-major
        float* at = smem + 1024;      // [32][64] k-major
        int to = t & 15;              // 16 o-groups of 2
        int th = t >> 4;              // 16 h-groups of 4
        float acc[2][4] = {};
        const float* ab = a + (size_t)b * NCM * NL + side * 64;
        for (int kc = 0; kc < NCM; kc += 32) {
            {
                int oi = t & 31, k0 = (t >> 5) * 4;
                float4 wv = *(const float4*)(wsel + (size_t)(ot * 32 + oi) * NCM + kc + k0);
                wt[(k0 + 0) * 32 + oi] = wv.x; wt[(k0 + 1) * 32 + oi] = wv.y;
                wt[(k0 + 2) * 32 + oi] = wv.z; wt[(k0 + 3) * 32 + oi] = wv.w;
            }
            #pragma unroll
            for (int i = 0; i < 2; ++i) {
                int f = t + i * 256;
                int ki = f >> 4, h4 = f & 15;
                *(float4*)&at[ki * 64 + h4 * 4] =
                    *(const float4*)(ab + (size_t)(kc + ki) * NL + h4 * 4);
            }
            __syncthreads();
            #pragma unroll
            for (int kj = 0; kj < 32; ++kj) {
                float2 wv = *(const float2*)&wt[kj * 32 + to * 2];
                float4 av = *(const float4*)&at[kj * 64 + th * 4];
                float aa[4] = {av.x, av.y, av.z, av.w};
                #pragma unroll
                for (int j = 0; j < 4; ++j) {
                    acc[0][j] += wv.x * aa[j];
                    acc[1][j] += wv.y * aa[j];
                }
            }
            __syncthreads();
        }
        #pragma unroll
        for (int i = 0; i < 2; ++i) {
            int o = ot * 32 + to * 2 + i;
            float bias = bsel[o];
            #pragma unroll
            for (int j = 0; j < 4; ++j) {
                float v = acc[i][j] + bias;
                float g = 1.f / (1.f + __expf(-v));
                gsel[((size_t)b * NCO + o) * 64 + th * 4 + j] = g;
            }
        }
    }
    grid.sync();

    // ---------------- Phase 4: apply ----------------
    for (int plane = blk; plane < NPLANES; plane += G) {
        const float4* px = (const float4*)(x + (size_t)plane * 4096);
        v4f* po = (v4f*)(out + (size_t)plane * 4096);
        const float* ghp = gh + (size_t)plane * 64;
        const float4* gwp = (const float4*)(gw + (size_t)plane * 64);
        #pragma unroll
        for (int i = 0; i < 4; ++i) {
            int f = t + i * 256;
            int row = f >> 4, w4 = f & 15;
            float4 v = px[f];
            float g = ghp[row];
            float4 gv = gwp[w4];
            v4f r;
            r.x = v.x * g * gv.x; r.y = v.y * g * gv.y;
            r.z = v.z * g * gv.z; r.w = v.w * g * gv.w;
            __builtin_nontemporal_store(r, po + f);
        }
    }
}

// ================= Fallback: separate kernels (round-3 proven path) ==========
__global__ __launch_bounds__(256) void k_pool(const float* __restrict__ x,
                                              float* __restrict__ pool) {
    int plane = blockIdx.x;
    const float4* px = (const float4*)(x + (size_t)plane * 4096);
    int t = threadIdx.x;
    __shared__ float smem[256 * 4];
    float4 csum = make_float4(0.f, 0.f, 0.f, 0.f);
    for (int i = 0; i < 4; ++i) {
        int f = t + i * 256;
        float4 v = px[f];
        csum.x += v.x; csum.y += v.y; csum.z += v.z; csum.w += v.w;
        float s = v.x + v.y + v.z + v.w;
        s += __shfl_xor(s, 1);
        s += __shfl_xor(s, 2);
        s += __shfl_xor(s, 4);
        s += __shfl_xor(s, 8);
        if ((t & 15) == 0)
            pool[(size_t)plane * NL + (t >> 4) + 16 * i] = s * 0.015625f;
    }
    ((float4*)smem)[t] = csum;
    __syncthreads();
    if (t < 64) {
        float acc = 0.f;
        #pragma unroll
        for (int g = 0; g < 16; ++g)
            acc += smem[((t >> 2) + 16 * g) * 4 + (t & 3)];
        pool[(size_t)plane * NL + 64 + t] = acc * 0.015625f;
    }
}

__global__ __launch_bounds__(256) void k_mlp1(const float* __restrict__ pool,
                                              const float* __restrict__ w1,
                                              const float* __restrict__ b1,
                                              const float* __restrict__ gam,
                                              const float* __restrict__ bet,
                                              const float* __restrict__ mu,
                                              const float* __restrict__ var,
                                              float* __restrict__ a) {
    int b = blockIdx.x, m0 = blockIdx.y * 16;
    int t = threadIdx.x;
    __shared__ float w1t[32][16];
    __shared__ float pt[32][NL];
    const float* poolb = pool + (size_t)b * NC * NL;
    int tm = t & 7, tl = t >> 3;
    float acc[2][4] = {};
    for (int cc = 0; cc < NC; cc += 32) {
        {
            int mi = t & 15, c0 = (t >> 4) * 2;
            float2 wv = *(const float2*)(w1 + (size_t)(m0 + mi) * NC + cc + c0);
            w1t[c0 + 0][mi] = wv.x; w1t[c0 + 1][mi] = wv.y;
        }
        #pragma unroll
        for (int i = 0; i < 4; ++i) {
            int f = t + i * 256;
            int ci = f >> 5, l4 = f & 31;
            *(float4*)&pt[ci][l4 * 4] =
                *(const float4*)(poolb + (size_t)(cc + ci) * NL + l4 * 4);
        }
        __syncthreads();
        #pragma unroll
        for (int cj = 0; cj < 32; ++cj) {
            float2 wv = *(const float2*)&w1t[cj][tm * 2];
            float4 pv = *(const float4*)&pt[cj][tl * 4];
            float pa[4] = {pv.x, pv.y, pv.z, pv.w};
            #pragma unroll
            for (int j = 0; j < 4; ++j) {
                acc[0][j] += wv.x * pa[j];
                acc[1][j] += wv.y * pa[j];
            }
        }
        __syncthreads();
    }
    #pragma unroll
    for (int i = 0; i < 2; ++i) {
        int m = m0 + tm * 2 + i;
        float scale = gam[m] * rsqrtf(var[m] + 1e-5f);
        float base = b1[m] - mu[m];
        float bb = bet[m];
        #pragma unroll
        for (int j = 0; j < 4; ++j) {
            float y = (acc[i][j] + base) * scale + bb;
            float hs = y * fminf(fmaxf(y + 3.f, 0.f), 6.f) * (1.f / 6.f);
            a[(size_t)b * NCM * NL + (size_t)m * NL + tl * 4 + j] = hs;
        }
    }
}

__global__ __launch_bounds__(256) void k_gate(const float* __restrict__ a,
                                              const float* __restrict__ w2,
                                              const float* __restrict__ b2,
                                              const float* __restrict__ w3,
                                              const float* __restrict__ b3,
                                              float* __restrict__ gh,
                                              float* __restrict__ gw) {
    int b = blockIdx.x, side = blockIdx.y, ot = blockIdx.z;
    const float* wsel = side ? w3 : w2;
    const float* bsel = side ? b3 : b2;
    float* gsel = side ? gw : gh;
    int t = threadIdx.x;
    __shared__ float wt[32][32];
    __shared__ float at[32][64];
    int to = t & 15, th = t >> 4;
    float acc[2][4] = {};
    const float* ab = a + (size_t)b * NCM * NL + side * 64;
    for (int kc = 0; kc < NCM; kc += 32) {
        {
            int oi = t & 31, k0 = (t >> 5) * 4;
            float4 wv = *(const float4*)(wsel + (size_t)(ot * 32 + oi) * NCM + kc + k0);
            wt[k0 + 0][oi] = wv.x; wt[k0 + 1][oi] = wv.y;
            wt[k0 + 2][oi] = wv.z; wt[k0 + 3][oi] = wv.w;
        }
        #pragma unroll
        for (int i = 0; i < 2; ++i) {
            int f = t + i * 256;
            int ki = f >> 4, h4 = f & 15;
            *(float4*)&at[ki][h4 * 4] =
                *(const float4*)(ab + (size_t)(kc + ki) * NL + h4 * 4);
        }
        __syncthreads();
        #pragma unroll
        for (int kj = 0; kj < 32; ++kj) {
            float2 wv = *(const float2*)&wt[kj][to * 2];
            float4 av = *(const float4*)&at[kj][th * 4];
            float aa[4] = {av.x, av.y, av.z, av.w};
            #pragma unroll
            for (int j = 0; j < 4; ++j) {
                acc[0][j] += wv.x * aa[j];
                acc[1][j] += wv.y * aa[j];
            }
        }
        __syncthreads();
    }
    #pragma unroll
    for (int i = 0; i < 2; ++i) {
        int o = ot * 32 + to * 2 + i;
        float bias = bsel[o];
        #pragma unroll
        for (int j = 0; j < 4; ++j) {
            float v = acc[i][j] + bias;
            float g = 1.f / (1.f + __expf(-v));
            gsel[((size_t)b * NCO + o) * 64 + th * 4 + j] = g;
        }
    }
}

__global__ __launch_bounds__(256) void k_apply(const float* __restrict__ x,
                                               const float* __restrict__ gh,
                                               const float* __restrict__ gw,
                                               float* __restrict__ out) {
    int plane = blockIdx.x;
    int t = threadIdx.x;
    const float4* px = (const float4*)(x + (size_t)plane * 4096);
    v4f* po = (v4f*)(out + (size_t)plane * 4096);
    const float* ghp = gh + (size_t)plane * 64;
    const float4* gwp = (const float4*)(gw + (size_t)plane * 64);
    #pragma unroll
    for (int i = 0; i < 4; ++i) {
        int f = t + i * 256;
        int row = f >> 4, w4 = f & 15;
        float4 v = px[f];
        float g = ghp[row];
        float4 gv = gwp[w4];
        v4f r;
        r.x = v.x * g * gv.x; r.y = v.y * g * gv.y;
        r.z = v.z * g * gv.z; r.w = v.w * g * gv.w;
        __builtin_nontemporal_store(r, po + f);
    }
}

extern "C" void kernel_launch(void* const* d_in, const int* in_sizes, int n_in,
                              void* d_out, int out_size, void* d_ws, size_t ws_size,
                              hipStream_t stream) {
    const float* x   = (const float*)d_in[0];
    const float* w1  = (const float*)d_in[1];
    const float* b1  = (const float*)d_in[2];
    const float* gam = (const float*)d_in[3];
    const float* bet = (const float*)d_in[4];
    const float* mu  = (const float*)d_in[5];
    const float* var = (const float*)d_in[6];
    const float* w2  = (const float*)d_in[7];
    const float* b2  = (const float*)d_in[8];
    const float* w3  = (const float*)d_in[9];
    const float* b3  = (const float*)d_in[10];
    float* ws   = (float*)d_ws;
    float* pool = ws;                       // 32*256*128 = 1,048,576 f
    float* a    = ws + 1048576;             // 32*128*128 =   524,288 f
    float* gh   = ws + 1572864;             // 32*256*64  =   524,288 f
    float* gw   = ws + 2097152;             // 32*256*64  =   524,288 f
    float* out  = (float*)d_out;

    // Size cooperative grid from actual occupancy (co-residency required).
    int maxBlk = 0;
    hipError_t oe = hipOccupancyMaxActiveBlocksPerMultiprocessor(
        &maxBlk, k_fused, 256, 0);
    int G = (oe == hipSuccess && maxBlk > 0) ? maxBlk * 256 : 512;
    if (G > 1024) G = 1024;

    void* args[] = {(void*)&x, (void*)&w1, (void*)&b1, (void*)&gam, (void*)&bet,
                    (void*)&mu, (void*)&var, (void*)&w2, (void*)&b2, (void*)&w3,
                    (void*)&b3, (void*)&pool, (void*)&a, (void*)&gh, (void*)&gw,
                    (void*)&out};
    hipError_t le = hipLaunchCooperativeKernel((const void*)k_fused, dim3(G),
                                               dim3(256), args, 0, stream);
    if (le != hipSuccess) {
        // Fallback: proven 4-kernel path.
        k_pool<<<NPLANES, 256, 0, stream>>>(x, pool);
        k_mlp1<<<dim3(NB, 8), 256, 0, stream>>>(pool, w1, b1, gam, bet, mu, var, a);
        k_gate<<<dim3(NB, 2, 8), 256, 0, stream>>>(a, w2, b2, w3, b3, gh, gw);
        k_apply<<<NPLANES, 256, 0, stream>>>(x, gh, gw, out);
    }
}

// Round 6
// 85.868 us; speedup vs baseline: 2.8756x; 2.8756x over previous
//
#include <hip/hip_runtime.h>

#define NB 32
#define NC 256
#define NL 128   // NH+NW
#define NCM 128
#define NCO 256
#define NPLANES (NB * NC)   // 8192

// ---------------- Kernel 1: H/W mean pooling ----------------
// grid: 2048 blocks, 4 contiguous planes per block (64 KB contiguous reads).
// pool layout: [b][c][l], l<64 = mean over W (xh), l>=64 = mean over H (xw)
__global__ __launch_bounds__(256) void k_pool(const float* __restrict__ x,
                                              float* __restrict__ pool) {
    int t = threadIdx.x;
    __shared__ float smem[1024];
    #pragma unroll
    for (int p = 0; p < 4; ++p) {
        int plane = blockIdx.x * 4 + p;          // b*NC + c
        const float4* px = (const float4*)(x + (size_t)plane * 4096);
        float4 csum = make_float4(0.f, 0.f, 0.f, 0.f);
        #pragma unroll
        for (int i = 0; i < 4; ++i) {
            int f = t + i * 256;                 // float4 index in plane
            float4 v = px[f];
            csum.x += v.x; csum.y += v.y; csum.z += v.z; csum.w += v.w;
            float s = v.x + v.y + v.z + v.w;     // 4 w-elems
            s += __shfl_xor(s, 1);
            s += __shfl_xor(s, 2);
            s += __shfl_xor(s, 4);
            s += __shfl_xor(s, 8);               // 16-lane group = full row
            if ((t & 15) == 0)
                pool[(size_t)plane * NL + (t >> 4) + 16 * i] = s * 0.015625f; // xh
        }
        ((float4*)smem)[t] = csum;
        __syncthreads();
        if (t < 64) {
            float acc = 0.f;
            #pragma unroll
            for (int g = 0; g < 16; ++g)
                acc += smem[((t >> 2) + 16 * g) * 4 + (t & 3)];
            pool[(size_t)plane * NL + 64 + t] = acc * 0.015625f;  // xw
        }
        __syncthreads();
    }
}

// ---------------- Kernel 2: y = w1 @ pool, BN, hswish ----------------
// grid: (NB, 8) — 16m-tile each; block 256 threads; thread: 2m x 4l
__global__ __launch_bounds__(256) void k_mlp1(const float* __restrict__ pool,
                                              const float* __restrict__ w1,
                                              const float* __restrict__ b1,
                                              const float* __restrict__ gam,
                                              const float* __restrict__ bet,
                                              const float* __restrict__ mu,
                                              const float* __restrict__ var,
                                              float* __restrict__ a) {
    int b = blockIdx.x, m0 = blockIdx.y * 16;
    int t = threadIdx.x;
    __shared__ float w1t[32][16];   // [c][m]
    __shared__ float pt[32][NL];    // [c][l]
    const float* poolb = pool + (size_t)b * NC * NL;
    int tm = t & 7;                 // 8 m-groups of 2
    int tl = t >> 3;                // 32 l-groups of 4
    float acc[2][4] = {};

    for (int cc = 0; cc < NC; cc += 32) {
        {
            int mi = t & 15, c0 = (t >> 4) * 2;
            float2 wv = *(const float2*)(w1 + (size_t)(m0 + mi) * NC + cc + c0);
            w1t[c0 + 0][mi] = wv.x; w1t[c0 + 1][mi] = wv.y;
        }
        #pragma unroll
        for (int i = 0; i < 4; ++i) {
            int f = t + i * 256;
            int ci = f >> 5, l4 = f & 31;
            *(float4*)&pt[ci][l4 * 4] =
                *(const float4*)(poolb + (size_t)(cc + ci) * NL + l4 * 4);
        }
        __syncthreads();
        #pragma unroll
        for (int cj = 0; cj < 32; ++cj) {
            float2 wv = *(const float2*)&w1t[cj][tm * 2];
            float4 pv = *(const float4*)&pt[cj][tl * 4];
            float pa[4] = {pv.x, pv.y, pv.z, pv.w};
            #pragma unroll
            for (int j = 0; j < 4; ++j) {
                acc[0][j] += wv.x * pa[j];
                acc[1][j] += wv.y * pa[j];
            }
        }
        __syncthreads();
    }
    #pragma unroll
    for (int i = 0; i < 2; ++i) {
        int m = m0 + tm * 2 + i;
        float scale = gam[m] * rsqrtf(var[m] + 1e-5f);
        float base = b1[m] - mu[m];
        float bb = bet[m];
        #pragma unroll
        for (int j = 0; j < 4; ++j) {
            float y = (acc[i][j] + base) * scale + bb;
            float hs = y * fminf(fmaxf(y + 3.f, 0.f), 6.f) * (1.f / 6.f);
            a[(size_t)b * NCM * NL + (size_t)m * NL + tl * 4 + j] = hs;
        }
    }
}

// ---------------- Kernel 3: gh/gw = sigmoid(w @ a + b) ----------------
// grid: (NB, 2 sides, 8 o-tiles); block 256; thread 2o x 4h
__global__ __launch_bounds__(256) void k_gate(const float* __restrict__ a,
                                              const float* __restrict__ w2,
                                              const float* __restrict__ b2,
                                              const float* __restrict__ w3,
                                              const float* __restrict__ b3,
                                              float* __restrict__ gh,
                                              float* __restrict__ gw) {
    int b = blockIdx.x, side = blockIdx.y, ot = blockIdx.z;
    const float* wsel = side ? w3 : w2;
    const float* bsel = side ? b3 : b2;
    float* gsel = side ? gw : gh;
    int t = threadIdx.x;
    __shared__ float wt[32][32];   // [k][o]
    __shared__ float at[32][64];   // [k][h]
    int to = t & 15;               // 16 o-groups of 2
    int th = t >> 4;               // 16 h-groups of 4
    float acc[2][4] = {};
    const float* ab = a + (size_t)b * NCM * NL + side * 64;

    for (int kc = 0; kc < NCM; kc += 32) {
        {
            int oi = t & 31, k0 = (t >> 5) * 4;
            float4 wv = *(const float4*)(wsel + (size_t)(ot * 32 + oi) * NCM + kc + k0);
            wt[k0 + 0][oi] = wv.x; wt[k0 + 1][oi] = wv.y;
            wt[k0 + 2][oi] = wv.z; wt[k0 + 3][oi] = wv.w;
        }
        #pragma unroll
        for (int i = 0; i < 2; ++i) {
            int f = t + i * 256;
            int ki = f >> 4, h4 = f & 15;
            *(float4*)&at[ki][h4 * 4] =
                *(const float4*)(ab + (size_t)(kc + ki) * NL + h4 * 4);
        }
        __syncthreads();
        #pragma unroll
        for (int kj = 0; kj < 32; ++kj) {
            float2 wv = *(const float2*)&wt[kj][to * 2];
            float4 av = *(const float4*)&at[kj][th * 4];
            float aa[4] = {av.x, av.y, av.z, av.w};
            #pragma unroll
            for (int j = 0; j < 4; ++j) {
                acc[0][j] += wv.x * aa[j];
                acc[1][j] += wv.y * aa[j];
            }
        }
        __syncthreads();
    }
    #pragma unroll
    for (int i = 0; i < 2; ++i) {
        int o = ot * 32 + to * 2 + i;
        float bias = bsel[o];
        #pragma unroll
        for (int j = 0; j < 4; ++j) {
            float v = acc[i][j] + bias;
            float g = 1.f / (1.f + __expf(-v));
            gsel[((size_t)b * NCO + o) * 64 + th * 4 + j] = g;
        }
    }
}

// ---------------- Kernel 4: out = x * gh[h] * gw[w] ----------------
// grid: 4096 blocks, 2 contiguous planes per block. Plain float4 stores
// (L2 write-combining); x read expected L3-resident from k_pool.
__global__ __launch_bounds__(256) void k_apply(const float* __restrict__ x,
                                               const float* __restrict__ gh,
                                               const float* __restrict__ gw,
                                               float* __restrict__ out) {
    int t = threadIdx.x;
    #pragma unroll
    for (int p = 0; p < 2; ++p) {
        int plane = blockIdx.x * 2 + p;      // b*NC + c (o == c since Co==C)
        const float4* px = (const float4*)(x + (size_t)plane * 4096);
        float4* po = (float4*)(out + (size_t)plane * 4096);
        const float* ghp = gh + (size_t)plane * 64;
        const float4* gwp = (const float4*)(gw + (size_t)plane * 64);
        #pragma unroll
        for (int i = 0; i < 4; ++i) {
            int f = t + i * 256;
            int row = f >> 4, w4 = f & 15;
            float4 v = px[f];
            float g = ghp[row];
            float4 gv = gwp[w4];
            v.x *= g * gv.x; v.y *= g * gv.y;
            v.z *= g * gv.z; v.w *= g * gv.w;
            po[f] = v;
        }
    }
}

extern "C" void kernel_launch(void* const* d_in, const int* in_sizes, int n_in,
                              void* d_out, int out_size, void* d_ws, size_t ws_size,
                              hipStream_t stream) {
    const float* x   = (const float*)d_in[0];
    const float* w1  = (const float*)d_in[1];
    const float* b1  = (const float*)d_in[2];
    const float* gam = (const float*)d_in[3];
    const float* bet = (const float*)d_in[4];
    const float* mu  = (const float*)d_in[5];
    const float* var = (const float*)d_in[6];
    const float* w2  = (const float*)d_in[7];
    const float* b2  = (const float*)d_in[8];
    const float* w3  = (const float*)d_in[9];
    const float* b3  = (const float*)d_in[10];
    float* ws   = (float*)d_ws;
    float* pool = ws;                       // 32*256*128 = 1,048,576 f
    float* a    = ws + 1048576;             // 32*128*128 =   524,288 f
    float* gh   = ws + 1572864;             // 32*256*64  =   524,288 f
    float* gw   = ws + 2097152;             // 32*256*64  =   524,288 f
    float* out  = (float*)d_out;

    k_pool<<<NPLANES / 4, 256, 0, stream>>>(x, pool);
    k_mlp1<<<dim3(NB, 8), 256, 0, stream>>>(pool, w1, b1, gam, bet, mu, var, a);
    k_gate<<<dim3(NB, 2, 8), 256, 0, stream>>>(a, w2, b2, w3, b3, gh, gw);
    k_apply<<<NPLANES / 2, 256, 0, stream>>>(x, gh, gw, out);
}